// Round 13
// baseline (491.302 us; speedup 1.0000x reference)
//
#include <hip/hip_runtime.h>

#define NN 100000
#define NE 1600000
#define DIN 128
#define HDIM 64
#define DOUT 40
#define EPS 1e-5f
#define NXCD 8
#define CAP 64                  // per-node bucket capacity; deg~Poisson(16), P(>64)~1e-19
#define NSH 4                   // channel shards (16 ch = 32B slice each)
#define SSTR ((NN + 1) * 16)    // ushorts per shard slice (+pad row)

typedef int int4v __attribute__((ext_vector_type(4)));
typedef float f4v __attribute__((ext_vector_type(4)));

__device__ __forceinline__ float bf2f(unsigned short v) {
    return __uint_as_float(((unsigned int)v) << 16);
}
__device__ __forceinline__ unsigned short f2bf(float f) {
    unsigned int u = __float_as_uint(f);
    u += 0x7FFFu + ((u >> 16) & 1u);   // round-to-nearest-even
    return (unsigned short)(u >> 16);
}

__device__ __forceinline__ int ntl(const int* p) { return __builtin_nontemporal_load(p); }
__device__ __forceinline__ int4v ntl4(const int4v* p) { return __builtin_nontemporal_load(p); }
__device__ __forceinline__ f4v ntlf4(const f4v* p) { return __builtin_nontemporal_load(p); }

// ---------------- bucket fill (XCD-sharded, nt streams) ---------------------
__global__ __launch_bounds__(256) void fill_kernel(const int* __restrict__ ei,
                                                   int* __restrict__ cnt,
                                                   int* __restrict__ esrc) {
    const int xcd = blockIdx.x & (NXCD - 1);
    const int lo = xcd * (NN / NXCD);
    const int hi = (xcd == NXCD - 1) ? NN : lo + (NN / NXCD);
    const int slot = blockIdx.x >> 3;
    const int nslot = gridDim.x >> 3;
    const int4v* d4 = (const int4v*)(ei + NE);
    for (int e4 = slot * blockDim.x + threadIdx.x; e4 < NE / 4; e4 += nslot * blockDim.x) {
        int4v d = ntl4(d4 + e4);
#pragma unroll
        for (int k = 0; k < 4; ++k) {
            int dd = d[k];
            if (dd >= lo && dd < hi) {
                int pos = atomicAdd(&cnt[dd], 1);
                if (pos < CAP) {
                    int s = ntl(ei + 4 * e4 + k);
                    __builtin_nontemporal_store(s, &esrc[(dd << 6) + pos]);
                }
            }
        }
    }
}

__global__ __launch_bounds__(256) void dis_kernel(const int* __restrict__ cnt,
                                                  float* __restrict__ dis) {
    for (int i = blockIdx.x * blockDim.x + threadIdx.x; i < NN; i += gridDim.x * blockDim.x)
        dis[i] = rsqrtf((float)(cnt[i] + 1));   // +1 self loop
}

// ---------------- dense GEMM -> channel-sliced bf16 h2s ---------------------
// h2s[shard][row][16ch]: lane (=output channel) writes its 2B to slice lane>>4.
template <int K, int TR, bool BN, bool NTL>
__global__ __launch_bounds__(256) void gemm_lds(const float* __restrict__ x,
                                                const float* __restrict__ W,
                                                const float* __restrict__ dis,
                                                const float* __restrict__ sc,
                                                const float* __restrict__ sh,
                                                unsigned short* __restrict__ h2) {
    __shared__ float xs[TR][K];
    const int tid = threadIdx.x;
    const int lane = tid & 63;
    const int wv = tid >> 6;
    float w[K];
#pragma unroll
    for (int k = 0; k < K; ++k) w[k] = W[k * 64 + lane];

    float4 scv, shv;
    if (BN) {
        const int c4 = tid & (K / 4 - 1);
        scv = ((const float4*)sc)[c4];
        shv = ((const float4*)sh)[c4];
    }

    const int row0 = blockIdx.x * TR;
    const int remRows = NN - row0;
    const int nvec = ((remRows >= TR) ? TR : remRows) * K / 4;
    const f4v* srcv = (const f4v*)(x + (long long)row0 * K);
    f4v* dstv = (f4v*)&xs[0][0];
    for (int i = tid; i < nvec; i += 256) {
        f4v v = NTL ? ntlf4(srcv + i) : srcv[i];
        if (BN) {
            v.x = fmaxf(fmaf(v.x, scv.x, shv.x), 0.f);
            v.y = fmaxf(fmaf(v.y, scv.y, shv.y), 0.f);
            v.z = fmaxf(fmaf(v.z, scv.z, shv.z), 0.f);
            v.w = fmaxf(fmaf(v.w, scv.w, shv.w), 0.f);
        }
        dstv[i] = v;
    }
    __syncthreads();

    unsigned short* hout = h2 + (lane >> 4) * SSTR + (lane & 15);
    const int rpw = TR / 4;
#pragma unroll
    for (int rr = 0; rr < rpw; ++rr) {
        const int r = wv * rpw + rr;
        const int row = row0 + r;
        if (row >= NN) break;
        float a0 = 0.f, a1 = 0.f, a2 = 0.f, a3 = 0.f;
#pragma unroll
        for (int k = 0; k < K; k += 4) {
            float4 xv = *(const float4*)&xs[r][k];
            a0 = fmaf(xv.x, w[k + 0], a0);
            a1 = fmaf(xv.y, w[k + 1], a1);
            a2 = fmaf(xv.z, w[k + 2], a2);
            a3 = fmaf(xv.w, w[k + 3], a3);
        }
        hout[row * 16] = f2bf(((a0 + a1) + (a2 + a3)) * dis[row]);
    }
}

// ---------------- channel-sharded bucket gather -----------------------------
// shard g = blockIdx&3 -> gathers confined to a 3.2MB contiguous slice that
// stays L2-resident on the XCD pair running shard g. Wave = 8 nodes x 8 lanes
// (ushort2 per lane). Loop bound = wave-max degree; stale/pad gathers clamp
// to zeroed pad row NN.
__global__ __launch_bounds__(256) void agg_csr(const int* __restrict__ cnt,
                                               const int* __restrict__ esrc,
                                               const float* __restrict__ dis,
                                               const unsigned short* __restrict__ h2,
                                               float* __restrict__ y) {
    const int tid = threadIdx.x;
    const int g = blockIdx.x & (NSH - 1);
    const int blk = blockIdx.x >> 2;
    const int wv = tid >> 6;
    const int lane = tid & 63;
    const int node = blk * 32 + wv * 8 + (lane >> 3);
    const int cp = lane & 7;                    // channel-pair within slice
    const ushort2* hv = (const ushort2*)(h2 + g * SSTR);
    ushort2 p0 = hv[node * 8 + cp];
    float ax = bf2f(p0.x), ay = bf2f(p0.y);
    const int deg = min(cnt[node], CAP);
    int m = deg;
    m = max(m, __shfl_xor(m, 8));
    m = max(m, __shfl_xor(m, 16));
    m = max(m, __shfl_xor(m, 32));
    const int jb = node << 6;
#pragma unroll 8
    for (int t = 0; t < m; ++t) {
        int sv = esrc[jb + t];
        int s = (t < deg) ? sv : NN;
        ushort2 p = hv[s * 8 + cp];
        ax += bf2f(p.x);
        ay += bf2f(p.y);
    }
    float dn = dis[node];
    ((float2*)(y + node * 64))[g * 8 + cp] = make_float2(ax * dn, ay * dn);
}

// ---------------- layer-3 sharded gather + BN/JK-max (writes jk rows) -------
__global__ __launch_bounds__(256) void agg3_jk(const int* __restrict__ cnt,
                                               const int* __restrict__ esrc,
                                               const float* __restrict__ dis,
                                               const unsigned short* __restrict__ h2,
                                               const float* __restrict__ x1,
                                               const float* __restrict__ x2,
                                               const float* __restrict__ sc1,
                                               const float* __restrict__ sh1,
                                               const float* __restrict__ sc2,
                                               const float* __restrict__ sh2,
                                               const float* __restrict__ b3,
                                               float* __restrict__ jk) {
    const int tid = threadIdx.x;
    const int g = blockIdx.x & (NSH - 1);
    const int blk = blockIdx.x >> 2;
    const int wv = tid >> 6;
    const int lane = tid & 63;
    const int node = blk * 32 + wv * 8 + (lane >> 3);
    const int cp = lane & 7;
    const ushort2* hv = (const ushort2*)(h2 + g * SSTR);
    ushort2 p0 = hv[node * 8 + cp];
    float ax = bf2f(p0.x), ay = bf2f(p0.y);
    const int deg = min(cnt[node], CAP);
    int m = deg;
    m = max(m, __shfl_xor(m, 8));
    m = max(m, __shfl_xor(m, 16));
    m = max(m, __shfl_xor(m, 32));
    const int jb = node << 6;
#pragma unroll 8
    for (int t = 0; t < m; ++t) {
        int sv = esrc[jb + t];
        int s = (t < deg) ? sv : NN;
        ushort2 p = hv[s * 8 + cp];
        ax += bf2f(p.x);
        ay += bf2f(p.y);
    }
    const float dn = dis[node];
    const int c0 = g * 16 + cp * 2;
    float2 x1v = ((const float2*)(x1 + node * 64))[g * 8 + cp];
    float2 x2v = ((const float2*)(x2 + node * 64))[g * 8 + cp];
    float v3x = fmaf(ax, dn, b3[c0]);
    float v3y = fmaf(ay, dn, b3[c0 + 1]);
    float v1x = fmaxf(fmaf(x1v.x, sc1[c0], sh1[c0]), 0.f);
    float v1y = fmaxf(fmaf(x1v.y, sc1[c0 + 1], sh1[c0 + 1]), 0.f);
    float v2x = fmaxf(fmaf(x2v.x, sc2[c0], sh2[c0]), 0.f);
    float v2y = fmaxf(fmaf(x2v.y, sc2[c0 + 1], sh2[c0 + 1]), 0.f);
    ((float2*)(jk + node * 64))[g * 8 + cp] =
        make_float2(fmaxf(fmaxf(v1x, v2x), v3x), fmaxf(fmaxf(v1y, v2y), v3y));
}

// ---------------- final matvec: out = jk @ Wf + bf --------------------------
__global__ __launch_bounds__(256) void final_kernel(const float* __restrict__ jk,
                                                    const float* __restrict__ Wf,
                                                    const float* __restrict__ bf,
                                                    float* __restrict__ out) {
    __shared__ float m[4][64];
    const int tid = threadIdx.x;
    const int r = tid >> 6, c = tid & 63;
    const int row = blockIdx.x * 4 + r;
    m[r][c] = jk[row * 64 + c];
    __syncthreads();
    if (c < DOUT) {
        float acc = bf[c];
#pragma unroll
        for (int k = 0; k < 64; ++k) acc += m[r][k] * Wf[k * DOUT + c];
        out[row * DOUT + c] = acc;
    }
}

// ---------------- per-channel sum / sumsq ----------------
__global__ __launch_bounds__(256) void stats_kernel(const float* __restrict__ y, float* stats) {
    const int tid = threadIdx.x;
    const int c = tid & 63, rg = tid >> 6;
    float s = 0.f, s2 = 0.f;
    for (int row = blockIdx.x * 4 + rg; row < NN; row += gridDim.x * 4) {
        float v = y[row * 64 + c];
        s += v;
        s2 += v * v;
    }
    __shared__ float ls[256], ls2[256];
    ls[tid] = s; ls2[tid] = s2;
    __syncthreads();
    if (tid < 64) {
        s = ls[tid] + ls[tid + 64] + ls[tid + 128] + ls[tid + 192];
        s2 = ls2[tid] + ls2[tid + 64] + ls2[tid + 128] + ls2[tid + 192];
        atomicAdd(&stats[tid], s);
        atomicAdd(&stats[64 + tid], s2);
    }
}

// ---------------- BN coefficients ----------------
__global__ __launch_bounds__(64) void bn_coef(const float* __restrict__ stats,
                                              const float* __restrict__ g,
                                              const float* __restrict__ beta,
                                              float* __restrict__ sc,
                                              float* __restrict__ sh) {
    const int c = threadIdx.x;
    const float invN = 1.0f / NN;
    float m = stats[c] * invN;
    float var = stats[64 + c] * invN - m * m;
    float s = g[c] * rsqrtf(var + EPS);
    sc[c] = s;
    sh[c] = beta[c] - m * s;
}

extern "C" void kernel_launch(void* const* d_in, const int* in_sizes, int n_in,
                              void* d_out, int out_size, void* d_ws, size_t ws_size,
                              hipStream_t stream) {
    const float* node_feat = (const float*)d_in[0];
    const int*   ei        = (const int*)d_in[1];
    const float* W1 = (const float*)d_in[2];
    const float* g1 = (const float*)d_in[4];
    const float* beta1 = (const float*)d_in[5];
    const float* W2 = (const float*)d_in[6];
    const float* g2 = (const float*)d_in[8];
    const float* beta2 = (const float*)d_in[9];
    const float* W3 = (const float*)d_in[10];
    const float* b3 = (const float*)d_in[11];
    const float* Wf = (const float*)d_in[12];
    const float* bf = (const float*)d_in[13];
    float* out = (float*)d_out;

    // workspace layout
    float* ws  = (float*)d_ws;
    float* dis = ws;                                       // N
    unsigned short* h2 = (unsigned short*)(dis + NN);      // 4 * SSTR (sliced, +pad rows)
    float* x1  = (float*)(h2 + NSH * SSTR);                // N*64 f32
    float* x2  = x1 + NN * 64;
    float* jk  = x2 + NN * 64;                             // N*64 f32
    float* stats = jk + NN * 64;                           // 128
    float* sc1 = stats + 128;                              // 64
    float* sh1 = sc1 + 64;                                 // 64
    float* sc2 = sh1 + 64;                                 // 64
    float* sh2 = sc2 + 64;                                 // 64
    int* cnt  = (int*)(sh2 + 64);                          // N
    int* esrc = cnt + NN;                                  // N*CAP

    const int B = 256;
    const int gElem = 2048;
    const int gAgg = (NN / 32) * NSH;   // 12500 (32 nodes/block x 4 shards)
    const int gFin = NN / 4;            // 25000

    // ---- bucket build + normalization ----
    hipMemsetAsync(cnt, 0, NN * sizeof(int), stream);
    for (int g = 0; g < NSH; ++g)       // zero pad row of each slice
        hipMemsetAsync(h2 + g * SSTR + NN * 16, 0, 16 * sizeof(unsigned short), stream);
    fill_kernel<<<gElem, B, 0, stream>>>(ei, cnt, esrc);
    dis_kernel<<<512, B, 0, stream>>>(cnt, dis);

    // ---- layer 1 ----
    gemm_lds<DIN, 32, false, true><<<(NN + 31) / 32, B, 0, stream>>>(node_feat, W1, dis, nullptr, nullptr, h2);
    agg_csr<<<gAgg, B, 0, stream>>>(cnt, esrc, dis, h2, x1);
    hipMemsetAsync(stats, 0, 128 * sizeof(float), stream);
    stats_kernel<<<512, B, 0, stream>>>(x1, stats);
    bn_coef<<<1, 64, 0, stream>>>(stats, g1, beta1, sc1, sh1);

    // ---- layer 2 (BN1+ReLU fused into staging) ----
    gemm_lds<HDIM, 64, true, false><<<(NN + 63) / 64, B, 0, stream>>>(x1, W2, dis, sc1, sh1, h2);
    agg_csr<<<gAgg, B, 0, stream>>>(cnt, esrc, dis, h2, x2);
    hipMemsetAsync(stats, 0, 128 * sizeof(float), stream);
    stats_kernel<<<512, B, 0, stream>>>(x2, stats);
    bn_coef<<<1, 64, 0, stream>>>(stats, g2, beta2, sc2, sh2);

    // ---- layer 3 (BN2+ReLU fused; sharded agg + BN/JK, then matvec) ----
    gemm_lds<HDIM, 64, true, false><<<(NN + 63) / 64, B, 0, stream>>>(x2, W3, dis, sc2, sh2, h2);
    agg3_jk<<<gAgg, B, 0, stream>>>(cnt, esrc, dis, h2, x1, x2,
                                    sc1, sh1, sc2, sh2, b3, jk);
    final_kernel<<<gFin, B, 0, stream>>>(jk, Wf, bf, out);
}

// Round 14
// 407.093 us; speedup vs baseline: 1.2069x; 1.2069x over previous
//
#include <hip/hip_runtime.h>

#define NN 100000
#define NE 1600000
#define DIN 128
#define HDIM 64
#define DOUT 40
#define EPS 1e-5f
#define NXCD 8
#define CAP 64   // fixed per-node edge capacity; deg ~ Poisson(16), P(>64) ~ 1e-19

typedef int int4v __attribute__((ext_vector_type(4)));
typedef float f4v __attribute__((ext_vector_type(4)));

__device__ __forceinline__ float bf2f(unsigned short v) {
    return __uint_as_float(((unsigned int)v) << 16);
}
__device__ __forceinline__ unsigned short f2bf(float f) {
    unsigned int u = __float_as_uint(f);
    u += 0x7FFFu + ((u >> 16) & 1u);   // round-to-nearest-even
    return (unsigned short)(u >> 16);
}

// nontemporal loads ONLY for pure streams with zero reuse
__device__ __forceinline__ int ntl(const int* p) { return __builtin_nontemporal_load(p); }
__device__ __forceinline__ int4v ntl4(const int4v* p) { return __builtin_nontemporal_load(p); }
__device__ __forceinline__ f4v ntlf4(const f4v* p) { return __builtin_nontemporal_load(p); }

// ---------------- bucket fill (replaces count+scan+fill) --------------------
// XCD-sharded: shard p owns dst range p. ei reads are nt (no L2 allocate) so
// they don't evict the dirty esrc window; esrc stores are PLAIN so dirty
// lines sit in L2 (3.2MB/XCD window fits 4MB) and collect all ~16 sub-writes
// before one eviction. (r9's nt-store caused 15x write amplification.)
__global__ __launch_bounds__(256) void fill_kernel(const int* __restrict__ ei,
                                                   int* __restrict__ cnt,
                                                   int* __restrict__ esrc) {
    const int xcd = blockIdx.x & (NXCD - 1);
    const int lo = xcd * (NN / NXCD);
    const int hi = (xcd == NXCD - 1) ? NN : lo + (NN / NXCD);
    const int slot = blockIdx.x >> 3;
    const int nslot = gridDim.x >> 3;
    const int4v* d4 = (const int4v*)(ei + NE);
    for (int e4 = slot * blockDim.x + threadIdx.x; e4 < NE / 4; e4 += nslot * blockDim.x) {
        int4v d = ntl4(d4 + e4);
#pragma unroll
        for (int k = 0; k < 4; ++k) {
            int dd = d[k];
            if (dd >= lo && dd < hi) {
                int pos = atomicAdd(&cnt[dd], 1);
                if (pos < CAP) {
                    esrc[(dd << 6) + pos] = ntl(ei + 4 * e4 + k);
                }
            }
        }
    }
}

__global__ __launch_bounds__(256) void dis_kernel(const int* __restrict__ cnt,
                                                  float* __restrict__ dis) {
    for (int i = blockIdx.x * blockDim.x + threadIdx.x; i < NN; i += gridDim.x * blockDim.x)
        dis[i] = rsqrtf((float)(cnt[i] + 1));   // +1 self loop
}

// ---------------- dense GEMM: h2[N,64] = bf16( (bn?(x)[N,K] @ W[K,64]) * dis[row] )
template <int K, int TR, bool BN, bool NTL>
__global__ __launch_bounds__(256) void gemm_lds(const float* __restrict__ x,
                                                const float* __restrict__ W,
                                                const float* __restrict__ dis,
                                                const float* __restrict__ sc,
                                                const float* __restrict__ sh,
                                                unsigned short* __restrict__ h2) {
    __shared__ float xs[TR][K];
    const int tid = threadIdx.x;
    const int lane = tid & 63;
    const int wv = tid >> 6;
    float w[K];
#pragma unroll
    for (int k = 0; k < K; ++k) w[k] = W[k * 64 + lane];

    float4 scv, shv;
    if (BN) {
        const int c4 = tid & (K / 4 - 1);   // column group is constant per thread
        scv = ((const float4*)sc)[c4];
        shv = ((const float4*)sh)[c4];
    }

    const int row0 = blockIdx.x * TR;
    const int remRows = NN - row0;
    const int nvec = ((remRows >= TR) ? TR : remRows) * K / 4;
    const f4v* srcv = (const f4v*)(x + (long long)row0 * K);
    f4v* dstv = (f4v*)&xs[0][0];
    for (int i = tid; i < nvec; i += 256) {
        f4v v = NTL ? ntlf4(srcv + i) : srcv[i];
        if (BN) {
            v.x = fmaxf(fmaf(v.x, scv.x, shv.x), 0.f);
            v.y = fmaxf(fmaf(v.y, scv.y, shv.y), 0.f);
            v.z = fmaxf(fmaf(v.z, scv.z, shv.z), 0.f);
            v.w = fmaxf(fmaf(v.w, scv.w, shv.w), 0.f);
        }
        dstv[i] = v;
    }
    __syncthreads();

    const int rpw = TR / 4;
#pragma unroll
    for (int rr = 0; rr < rpw; ++rr) {
        const int r = wv * rpw + rr;
        const int row = row0 + r;
        if (row >= NN) break;
        float a0 = 0.f, a1 = 0.f, a2 = 0.f, a3 = 0.f;
#pragma unroll
        for (int k = 0; k < K; k += 4) {
            float4 xv = *(const float4*)&xs[r][k];
            a0 = fmaf(xv.x, w[k + 0], a0);
            a1 = fmaf(xv.y, w[k + 1], a1);
            a2 = fmaf(xv.z, w[k + 2], a2);
            a3 = fmaf(xv.w, w[k + 3], a3);
        }
        h2[row * 64 + lane] = f2bf(((a0 + a1) + (a2 + a3)) * dis[row]);
    }
}

// ---------------- bucket gather, half-wave: 2 nodes/wave --------------------
// Lane owns a channel pair (ushort2). jb = node*CAP is a constant; stale
// slots clamp to zeroed pad row NN before the gather.
__global__ __launch_bounds__(256) void agg_csr(const int* __restrict__ cnt,
                                               const int* __restrict__ esrc,
                                               const float* __restrict__ dis,
                                               const unsigned short* __restrict__ h2,
                                               float* __restrict__ y) {
    const int tid = threadIdx.x;
    const int wv = tid >> 6;
    const int lane = tid & 63;
    const int half = lane >> 5;
    const int c = lane & 31;                 // channel-pair index
    const int node = blockIdx.x * 8 + wv * 2 + half;
    const ushort2* h2v = (const ushort2*)h2; // row stride = 32 pairs
    ushort2 p0 = h2v[node * 32 + c];
    float ax = bf2f(p0.x), ay = bf2f(p0.y);
    const int deg = min(cnt[node], CAP);
    const int m = max(deg, __shfl_xor(deg, 32));
    const int jb = node << 6;                // node*CAP
#pragma unroll 8
    for (int t = 0; t < m; ++t) {
        int sv = esrc[jb + t];               // in-bounds (CAP slots); maybe stale
        int s = (t < deg) ? sv : NN;         // pad row NN is zeroed
        ushort2 p = h2v[s * 32 + c];
        ax += bf2f(p.x);
        ay += bf2f(p.y);
    }
    float dn = dis[node];
    ((float2*)(y + node * 64))[c] = make_float2(ax * dn, ay * dn);
}

// ---------------- layer-3 bucket gather fused with JK max + final -----------
__global__ __launch_bounds__(256) void agg_final(const int* __restrict__ cnt,
                                                 const int* __restrict__ esrc,
                                                 const float* __restrict__ dis,
                                                 const unsigned short* __restrict__ h2,
                                                 const float* __restrict__ x1,
                                                 const float* __restrict__ x2,
                                                 const float* __restrict__ sc1,
                                                 const float* __restrict__ sh1,
                                                 const float* __restrict__ sc2,
                                                 const float* __restrict__ sh2,
                                                 const float* __restrict__ b3,
                                                 const float* __restrict__ Wf,
                                                 const float* __restrict__ bf,
                                                 float* __restrict__ out) {
    __shared__ float m[8][64];
    const int tid = threadIdx.x;
    const int wv = tid >> 6;
    const int lane = tid & 63;
    const int half = lane >> 5;
    const int c = lane & 31;
    const int node = blockIdx.x * 8 + wv * 2 + half;
    const ushort2* h2v = (const ushort2*)h2;
    ushort2 p0 = h2v[node * 32 + c];
    float ax = bf2f(p0.x), ay = bf2f(p0.y);
    const int deg = min(cnt[node], CAP);
    const int mm = max(deg, __shfl_xor(deg, 32));
    const int jb = node << 6;
#pragma unroll 8
    for (int t = 0; t < mm; ++t) {
        int sv = esrc[jb + t];
        int s = (t < deg) ? sv : NN;
        ushort2 p = h2v[s * 32 + c];
        ax += bf2f(p.x);
        ay += bf2f(p.y);
    }
    const float dn = dis[node];
    const int c0 = 2 * c;
    const int o = node * 64 + c0;
    float2 x1v = *(const float2*)(x1 + o);
    float2 x2v = *(const float2*)(x2 + o);
    float v3x = fmaf(ax, dn, b3[c0]);
    float v3y = fmaf(ay, dn, b3[c0 + 1]);
    float v1x = fmaxf(fmaf(x1v.x, sc1[c0], sh1[c0]), 0.f);
    float v1y = fmaxf(fmaf(x1v.y, sc1[c0 + 1], sh1[c0 + 1]), 0.f);
    float v2x = fmaxf(fmaf(x2v.x, sc2[c0], sh2[c0]), 0.f);
    float v2y = fmaxf(fmaf(x2v.y, sc2[c0 + 1], sh2[c0 + 1]), 0.f);
    const int rl = wv * 2 + half;
    m[rl][c0] = fmaxf(fmaxf(v1x, v2x), v3x);
    m[rl][c0 + 1] = fmaxf(fmaxf(v1y, v2y), v3y);
    __syncthreads();
#pragma unroll
    for (int rr = wv; rr < 8; rr += 4) {
        if (lane < DOUT) {
            float a2 = bf[lane];
#pragma unroll
            for (int k = 0; k < 64; ++k) a2 += m[rr][k] * Wf[k * DOUT + lane];
            out[(blockIdx.x * 8 + rr) * DOUT + lane] = a2;
        }
    }
}

// ---------------- per-channel sum / sumsq ----------------
__global__ __launch_bounds__(256) void stats_kernel(const float* __restrict__ y, float* stats) {
    const int tid = threadIdx.x;
    const int c = tid & 63, rg = tid >> 6;
    float s = 0.f, s2 = 0.f;
    for (int row = blockIdx.x * 4 + rg; row < NN; row += gridDim.x * 4) {
        float v = y[row * 64 + c];
        s += v;
        s2 += v * v;
    }
    __shared__ float ls[256], ls2[256];
    ls[tid] = s; ls2[tid] = s2;
    __syncthreads();
    if (tid < 64) {
        s = ls[tid] + ls[tid + 64] + ls[tid + 128] + ls[tid + 192];
        s2 = ls2[tid] + ls2[tid + 64] + ls2[tid + 128] + ls2[tid + 192];
        atomicAdd(&stats[tid], s);
        atomicAdd(&stats[64 + tid], s2);
    }
}

// ---------------- BN coefficients ----------------
__global__ __launch_bounds__(64) void bn_coef(const float* __restrict__ stats,
                                              const float* __restrict__ g,
                                              const float* __restrict__ beta,
                                              float* __restrict__ sc,
                                              float* __restrict__ sh) {
    const int c = threadIdx.x;
    const float invN = 1.0f / NN;
    float m = stats[c] * invN;
    float var = stats[64 + c] * invN - m * m;
    float s = g[c] * rsqrtf(var + EPS);
    sc[c] = s;
    sh[c] = beta[c] - m * s;
}

extern "C" void kernel_launch(void* const* d_in, const int* in_sizes, int n_in,
                              void* d_out, int out_size, void* d_ws, size_t ws_size,
                              hipStream_t stream) {
    const float* node_feat = (const float*)d_in[0];
    const int*   ei        = (const int*)d_in[1];
    const float* W1 = (const float*)d_in[2];
    const float* g1 = (const float*)d_in[4];
    const float* beta1 = (const float*)d_in[5];
    const float* W2 = (const float*)d_in[6];
    const float* g2 = (const float*)d_in[8];
    const float* beta2 = (const float*)d_in[9];
    const float* W3 = (const float*)d_in[10];
    const float* b3 = (const float*)d_in[11];
    const float* Wf = (const float*)d_in[12];
    const float* bf = (const float*)d_in[13];
    float* out = (float*)d_out;

    // workspace layout
    float* ws  = (float*)d_ws;
    float* dis = ws;                                       // N
    unsigned short* h2 = (unsigned short*)(dis + NN);      // (N+1)*64 bf16 (+pad row)
    float* x1  = (float*)(h2 + (NN + 1) * 64);             // N*64 f32
    float* x2  = x1 + NN * 64;
    float* stats = x2 + NN * 64;                           // 128
    float* sc1 = stats + 128;                              // 64
    float* sh1 = sc1 + 64;                                 // 64
    float* sc2 = sh1 + 64;                                 // 64
    float* sh2 = sc2 + 64;                                 // 64
    int* cnt  = (int*)(sh2 + 64);                          // N
    int* esrc = cnt + NN;                                  // N*CAP

    const int B = 256;
    const int gElem = 2048;
    const int gAgg = NN / 8;      // 12500 (8 nodes per block)

    // ---- bucket build + normalization (no count/scan kernels) ----
    hipMemsetAsync(cnt, 0, NN * sizeof(int), stream);
    hipMemsetAsync(h2 + NN * 64, 0, 64 * sizeof(unsigned short), stream);  // pad row
    fill_kernel<<<gElem, B, 0, stream>>>(ei, cnt, esrc);
    dis_kernel<<<512, B, 0, stream>>>(cnt, dis);

    // ---- layer 1 ----
    gemm_lds<DIN, 32, false, true><<<(NN + 31) / 32, B, 0, stream>>>(node_feat, W1, dis, nullptr, nullptr, h2);
    agg_csr<<<gAgg, B, 0, stream>>>(cnt, esrc, dis, h2, x1);
    hipMemsetAsync(stats, 0, 128 * sizeof(float), stream);
    stats_kernel<<<512, B, 0, stream>>>(x1, stats);
    bn_coef<<<1, 64, 0, stream>>>(stats, g1, beta1, sc1, sh1);

    // ---- layer 2 (BN1+ReLU fused into staging) ----
    gemm_lds<HDIM, 64, true, false><<<(NN + 63) / 64, B, 0, stream>>>(x1, W2, dis, sc1, sh1, h2);
    agg_csr<<<gAgg, B, 0, stream>>>(cnt, esrc, dis, h2, x2);
    hipMemsetAsync(stats, 0, 128 * sizeof(float), stream);
    stats_kernel<<<512, B, 0, stream>>>(x2, stats);
    bn_coef<<<1, 64, 0, stream>>>(stats, g2, beta2, sc2, sh2);

    // ---- layer 3 (BN2+ReLU fused into staging; agg fused with JK+final) ----
    gemm_lds<HDIM, 64, true, false><<<(NN + 63) / 64, B, 0, stream>>>(x2, W3, dis, sc2, sh2, h2);
    agg_final<<<gAgg, B, 0, stream>>>(cnt, esrc, dis, h2, x1, x2,
                                      sc1, sh1, sc2, sh2, b3, Wf, bf, out);
}

// Round 15
// 381.176 us; speedup vs baseline: 1.2889x; 1.0680x over previous
//
#include <hip/hip_runtime.h>

#define NN 100000
#define NE 1600000
#define DIN 128
#define HDIM 64
#define DOUT 40
#define EPS 1e-5f
#define NXCD 8
#define CAP 64            // per-node bucket capacity; deg~Poisson(16), P(>64)~1e-19
#define NAGG (NN / 8)     // 12500 agg blocks (8 nodes each)

typedef int int4v __attribute__((ext_vector_type(4)));
typedef float f4v __attribute__((ext_vector_type(4)));
typedef unsigned short u16x8 __attribute__((ext_vector_type(8)));

__device__ __forceinline__ float bf2f(unsigned short v) {
    return __uint_as_float(((unsigned int)v) << 16);
}
__device__ __forceinline__ unsigned short f2bf(float f) {
    unsigned int u = __float_as_uint(f);
    u += 0x7FFFu + ((u >> 16) & 1u);   // round-to-nearest-even
    return (unsigned short)(u >> 16);
}

// nontemporal loads ONLY for pure streams with zero reuse
__device__ __forceinline__ int ntl(const int* p) { return __builtin_nontemporal_load(p); }
__device__ __forceinline__ int4v ntl4(const int4v* p) { return __builtin_nontemporal_load(p); }
__device__ __forceinline__ f4v ntlf4(const f4v* p) { return __builtin_nontemporal_load(p); }

// ---------------- bucket fill ------------------------------------------------
// XCD-sharded; nt reads for the ei streams (no L2 allocate), PLAIN stores for
// esrc so the 3.2MB/XCD dirty window sits in L2 and collects sub-writes.
__global__ __launch_bounds__(256) void fill_kernel(const int* __restrict__ ei,
                                                   int* __restrict__ cnt,
                                                   int* __restrict__ esrc) {
    const int xcd = blockIdx.x & (NXCD - 1);
    const int lo = xcd * (NN / NXCD);
    const int hi = (xcd == NXCD - 1) ? NN : lo + (NN / NXCD);
    const int slot = blockIdx.x >> 3;
    const int nslot = gridDim.x >> 3;
    const int4v* d4 = (const int4v*)(ei + NE);
    for (int e4 = slot * blockDim.x + threadIdx.x; e4 < NE / 4; e4 += nslot * blockDim.x) {
        int4v d = ntl4(d4 + e4);
#pragma unroll
        for (int k = 0; k < 4; ++k) {
            int dd = d[k];
            if (dd >= lo && dd < hi) {
                int pos = atomicAdd(&cnt[dd], 1);
                if (pos < CAP) {
                    esrc[(dd << 6) + pos] = ntl(ei + 4 * e4 + k);
                }
            }
        }
    }
}

__global__ __launch_bounds__(256) void dis_kernel(const int* __restrict__ cnt,
                                                  float* __restrict__ dis) {
    for (int i = blockIdx.x * blockDim.x + threadIdx.x; i < NN; i += gridDim.x * blockDim.x)
        dis[i] = rsqrtf((float)(cnt[i] + 1));   // +1 self loop
}

// ---------------- layer-1 GEMM (f32 input, nt): h2 = bf16((x@W1)*dis) -------
__global__ __launch_bounds__(256) void gemm_f32(const float* __restrict__ x,
                                                const float* __restrict__ W,
                                                const float* __restrict__ dis,
                                                unsigned short* __restrict__ h2) {
    const int K = DIN, TR = 32;
    __shared__ float xs[TR][DIN];
    const int tid = threadIdx.x;
    const int lane = tid & 63;
    const int wv = tid >> 6;
    float w[DIN];
#pragma unroll
    for (int k = 0; k < K; ++k) w[k] = W[k * 64 + lane];

    const int row0 = blockIdx.x * TR;
    const int nvec = TR * K / 4;   // NN % 32 == 0
    const f4v* srcv = (const f4v*)(x + (long long)row0 * K);
    f4v* dstv = (f4v*)&xs[0][0];
    for (int i = tid; i < nvec; i += 256) dstv[i] = ntlf4(srcv + i);
    __syncthreads();

    const int rpw = TR / 4;
#pragma unroll
    for (int rr = 0; rr < rpw; ++rr) {
        const int r = wv * rpw + rr;
        const int row = row0 + r;
        float a0 = 0.f, a1 = 0.f, a2 = 0.f, a3 = 0.f;
#pragma unroll
        for (int k = 0; k < K; k += 4) {
            float4 xv = *(const float4*)&xs[r][k];
            a0 = fmaf(xv.x, w[k + 0], a0);
            a1 = fmaf(xv.y, w[k + 1], a1);
            a2 = fmaf(xv.z, w[k + 2], a2);
            a3 = fmaf(xv.w, w[k + 3], a3);
        }
        h2[row * 64 + lane] = f2bf(((a0 + a1) + (a2 + a3)) * dis[row]);
    }
}

// ---------------- layer-2/3 GEMM (bf16 input + fused BN+ReLU) ---------------
// Staging: u16x8 loads, BN+ReLU applied during bf16->f32 convert. Channel
// group cg = tid&7 is iteration-invariant (256 % 8 == 0) -> coefs preloaded.
template <int TR>
__global__ __launch_bounds__(256) void gemm_bf16(const unsigned short* __restrict__ x16,
                                                 const float* __restrict__ W,
                                                 const float* __restrict__ dis,
                                                 const float* __restrict__ sc,
                                                 const float* __restrict__ sh,
                                                 unsigned short* __restrict__ h2) {
    __shared__ float xs[TR][HDIM];
    const int tid = threadIdx.x;
    const int lane = tid & 63;
    const int wv = tid >> 6;
    float w[HDIM];
#pragma unroll
    for (int k = 0; k < HDIM; ++k) w[k] = W[k * 64 + lane];

    const int cg = tid & 7;
    float scl[8], shl[8];
#pragma unroll
    for (int j = 0; j < 8; ++j) { scl[j] = sc[cg * 8 + j]; shl[j] = sh[cg * 8 + j]; }

    const int row0 = blockIdx.x * TR;
    const int remRows = NN - row0;
    const int nvec = ((remRows >= TR) ? TR : remRows) * 8;   // u16x8 per row = 8
    const u16x8* srcv = (const u16x8*)(x16 + (long long)row0 * 64);
    for (int i = tid; i < nvec; i += 256) {
        u16x8 v = srcv[i];
        float f[8];
#pragma unroll
        for (int j = 0; j < 8; ++j)
            f[j] = fmaxf(fmaf(bf2f(v[j]), scl[j], shl[j]), 0.f);
        float* dst = &xs[0][0] + i * 8;
        ((f4v*)dst)[0] = *(f4v*)&f[0];
        ((f4v*)dst)[1] = *(f4v*)&f[4];
    }
    __syncthreads();

    const int rpw = TR / 4;
#pragma unroll
    for (int rr = 0; rr < rpw; ++rr) {
        const int r = wv * rpw + rr;
        const int row = row0 + r;
        if (row >= NN) break;
        float a0 = 0.f, a1 = 0.f, a2 = 0.f, a3 = 0.f;
#pragma unroll
        for (int k = 0; k < HDIM; k += 4) {
            float4 xv = *(const float4*)&xs[r][k];
            a0 = fmaf(xv.x, w[k + 0], a0);
            a1 = fmaf(xv.y, w[k + 1], a1);
            a2 = fmaf(xv.z, w[k + 2], a2);
            a3 = fmaf(xv.w, w[k + 3], a3);
        }
        h2[row * 64 + lane] = f2bf(((a0 + a1) + (a2 + a3)) * dis[row]);
    }
}

// ---------------- bucket gather + bf16 y + fused block stats ----------------
// Half-wave per node (r9 form). Output y in bf16; block's 8x64 values reduced
// in LDS to per-block channel sum/sumsq partials (part[blk][128]).
__global__ __launch_bounds__(256) void agg_csr(const int* __restrict__ cnt,
                                               const int* __restrict__ esrc,
                                               const float* __restrict__ dis,
                                               const unsigned short* __restrict__ h2,
                                               unsigned short* __restrict__ y16,
                                               float* __restrict__ part) {
    __shared__ float sm[8][64];
    const int tid = threadIdx.x;
    const int wv = tid >> 6;
    const int lane = tid & 63;
    const int half = lane >> 5;
    const int c = lane & 31;                 // channel-pair index
    const int node = blockIdx.x * 8 + wv * 2 + half;
    const ushort2* h2v = (const ushort2*)h2;
    ushort2 p0 = h2v[node * 32 + c];
    float ax = bf2f(p0.x), ay = bf2f(p0.y);
    const int deg = min(cnt[node], CAP);
    const int m = max(deg, __shfl_xor(deg, 32));
    const int jb = node << 6;
#pragma unroll 8
    for (int t = 0; t < m; ++t) {
        int sv = esrc[jb + t];               // in-bounds (CAP slots); maybe stale
        int s = (t < deg) ? sv : NN;         // pad row NN is zeroed
        ushort2 p = h2v[s * 32 + c];
        ax += bf2f(p.x);
        ay += bf2f(p.y);
    }
    const float dn = dis[node];
    ax *= dn; ay *= dn;
    ushort2 o; o.x = f2bf(ax); o.y = f2bf(ay);
    ((ushort2*)y16)[node * 32 + c] = o;
    const int rl = wv * 2 + half;
    sm[rl][2 * c] = ax;
    sm[rl][2 * c + 1] = ay;
    __syncthreads();
    if (tid < 64) {
        float s = 0.f, s2 = 0.f;
#pragma unroll
        for (int r = 0; r < 8; ++r) {
            float v = sm[r][tid];
            s += v;
            s2 = fmaf(v, v, s2);
        }
        part[blockIdx.x * 128 + tid] = s;
        part[blockIdx.x * 128 + 64 + tid] = s2;
    }
}

// ---------------- partial-stats reduction (coalesced) -----------------------
__global__ __launch_bounds__(128) void stats_reduce(const float* __restrict__ part,
                                                    float* __restrict__ stats) {
    const int tid = threadIdx.x;
    const int r0 = blockIdx.x * (NAGG / 100);
    float s = 0.f;
    for (int r = r0; r < r0 + NAGG / 100; ++r) s += part[r * 128 + tid];
    atomicAdd(&stats[tid], s);
}

// ---------------- BN coefficients ----------------
__global__ __launch_bounds__(64) void bn_coef(const float* __restrict__ stats,
                                              const float* __restrict__ g,
                                              const float* __restrict__ beta,
                                              float* __restrict__ sc,
                                              float* __restrict__ sh) {
    const int c = threadIdx.x;
    const float invN = 1.0f / NN;
    float m = stats[c] * invN;
    float var = stats[64 + c] * invN - m * m;
    float s = g[c] * rsqrtf(var + EPS);
    sc[c] = s;
    sh[c] = beta[c] - m * s;
}

// ---------------- layer-3 gather + JK max (bf16 x1/x2) + final --------------
__global__ __launch_bounds__(256) void agg_final(const int* __restrict__ cnt,
                                                 const int* __restrict__ esrc,
                                                 const float* __restrict__ dis,
                                                 const unsigned short* __restrict__ h2,
                                                 const unsigned short* __restrict__ x1,
                                                 const unsigned short* __restrict__ x2,
                                                 const float* __restrict__ sc1,
                                                 const float* __restrict__ sh1,
                                                 const float* __restrict__ sc2,
                                                 const float* __restrict__ sh2,
                                                 const float* __restrict__ b3,
                                                 const float* __restrict__ Wf,
                                                 const float* __restrict__ bf,
                                                 float* __restrict__ out) {
    __shared__ float m[8][64];
    const int tid = threadIdx.x;
    const int wv = tid >> 6;
    const int lane = tid & 63;
    const int half = lane >> 5;
    const int c = lane & 31;
    const int node = blockIdx.x * 8 + wv * 2 + half;
    const ushort2* h2v = (const ushort2*)h2;
    ushort2 p0 = h2v[node * 32 + c];
    float ax = bf2f(p0.x), ay = bf2f(p0.y);
    const int deg = min(cnt[node], CAP);
    const int mm = max(deg, __shfl_xor(deg, 32));
    const int jb = node << 6;
#pragma unroll 8
    for (int t = 0; t < mm; ++t) {
        int sv = esrc[jb + t];
        int s = (t < deg) ? sv : NN;
        ushort2 p = h2v[s * 32 + c];
        ax += bf2f(p.x);
        ay += bf2f(p.y);
    }
    const float dn = dis[node];
    const int c0 = 2 * c;
    ushort2 x1u = ((const ushort2*)x1)[node * 32 + c];
    ushort2 x2u = ((const ushort2*)x2)[node * 32 + c];
    float v3x = fmaf(ax, dn, b3[c0]);
    float v3y = fmaf(ay, dn, b3[c0 + 1]);
    float v1x = fmaxf(fmaf(bf2f(x1u.x), sc1[c0], sh1[c0]), 0.f);
    float v1y = fmaxf(fmaf(bf2f(x1u.y), sc1[c0 + 1], sh1[c0 + 1]), 0.f);
    float v2x = fmaxf(fmaf(bf2f(x2u.x), sc2[c0], sh2[c0]), 0.f);
    float v2y = fmaxf(fmaf(bf2f(x2u.y), sc2[c0 + 1], sh2[c0 + 1]), 0.f);
    const int rl = wv * 2 + half;
    m[rl][c0] = fmaxf(fmaxf(v1x, v2x), v3x);
    m[rl][c0 + 1] = fmaxf(fmaxf(v1y, v2y), v3y);
    __syncthreads();
#pragma unroll
    for (int rr = wv; rr < 8; rr += 4) {
        if (lane < DOUT) {
            float a2 = bf[lane];
#pragma unroll
            for (int k = 0; k < 64; ++k) a2 += m[rr][k] * Wf[k * DOUT + lane];
            out[(blockIdx.x * 8 + rr) * DOUT + lane] = a2;
        }
    }
}

extern "C" void kernel_launch(void* const* d_in, const int* in_sizes, int n_in,
                              void* d_out, int out_size, void* d_ws, size_t ws_size,
                              hipStream_t stream) {
    const float* node_feat = (const float*)d_in[0];
    const int*   ei        = (const int*)d_in[1];
    const float* W1 = (const float*)d_in[2];
    const float* g1 = (const float*)d_in[4];
    const float* beta1 = (const float*)d_in[5];
    const float* W2 = (const float*)d_in[6];
    const float* g2 = (const float*)d_in[8];
    const float* beta2 = (const float*)d_in[9];
    const float* W3 = (const float*)d_in[10];
    const float* b3 = (const float*)d_in[11];
    const float* Wf = (const float*)d_in[12];
    const float* bf = (const float*)d_in[13];
    float* out = (float*)d_out;

    // workspace layout
    float* ws  = (float*)d_ws;
    float* dis = ws;                                       // N f32
    unsigned short* h2 = (unsigned short*)(dis + NN);      // (N+1)*64 bf16 (+pad row)
    unsigned short* x1 = h2 + (NN + 1) * 64;               // N*64 bf16
    unsigned short* x2 = x1 + NN * 64;                     // N*64 bf16
    float* part = (float*)(x2 + NN * 64);                  // NAGG*128 f32
    float* stats = part + NAGG * 128;                      // 128
    float* sc1 = stats + 128;                              // 64
    float* sh1 = sc1 + 64;                                 // 64
    float* sc2 = sh1 + 64;                                 // 64
    float* sh2 = sc2 + 64;                                 // 64
    int* cnt  = (int*)(sh2 + 64);                          // N
    int* esrc = cnt + NN;                                  // N*CAP

    const int B = 256;
    const int gElem = 2048;
    const int gAgg = NAGG;        // 12500

    // ---- bucket build + normalization ----
    hipMemsetAsync(cnt, 0, NN * sizeof(int), stream);
    hipMemsetAsync(h2 + NN * 64, 0, 64 * sizeof(unsigned short), stream);  // pad row
    fill_kernel<<<gElem, B, 0, stream>>>(ei, cnt, esrc);
    dis_kernel<<<512, B, 0, stream>>>(cnt, dis);

    // ---- layer 1 ----
    gemm_f32<<<NN / 32, B, 0, stream>>>(node_feat, W1, dis, h2);
    agg_csr<<<gAgg, B, 0, stream>>>(cnt, esrc, dis, h2, x1, part);
    hipMemsetAsync(stats, 0, 128 * sizeof(float), stream);
    stats_reduce<<<100, 128, 0, stream>>>(part, stats);
    bn_coef<<<1, 64, 0, stream>>>(stats, g1, beta1, sc1, sh1);

    // ---- layer 2 (BN1+ReLU fused into staging) ----
    gemm_bf16<64><<<(NN + 63) / 64, B, 0, stream>>>(x1, W2, dis, sc1, sh1, h2);
    agg_csr<<<gAgg, B, 0, stream>>>(cnt, esrc, dis, h2, x2, part);
    hipMemsetAsync(stats, 0, 128 * sizeof(float), stream);
    stats_reduce<<<100, 128, 0, stream>>>(part, stats);
    bn_coef<<<1, 64, 0, stream>>>(stats, g2, beta2, sc2, sh2);

    // ---- layer 3 (BN2+ReLU fused into staging; agg fused with JK+final) ----
    gemm_bf16<64><<<(NN + 63) / 64, B, 0, stream>>>(x2, W3, dis, sc2, sh2, h2);
    agg_final<<<gAgg, B, 0, stream>>>(cnt, esrc, dis, h2, x1, x2,
                                      sc1, sh1, sc2, sh2, b3, Wf, bf, out);
}

// Round 16
// 349.147 us; speedup vs baseline: 1.4072x; 1.0917x over previous
//
#include <hip/hip_runtime.h>

#define NN 100000
#define NE 1600000
#define DIN 128
#define HDIM 64
#define DOUT 40
#define EPS 1e-5f
#define NXCD 8
#define CAP 64            // per-node bucket capacity; deg~Poisson(16), P(>64)~1e-19
#define NAGG (NN / 8)     // 12500 agg blocks (8 nodes each)

typedef int int4v __attribute__((ext_vector_type(4)));
typedef float f4v __attribute__((ext_vector_type(4)));
typedef unsigned short u16x8 __attribute__((ext_vector_type(8)));

__device__ __forceinline__ float bf2f(unsigned short v) {
    return __uint_as_float(((unsigned int)v) << 16);
}
__device__ __forceinline__ unsigned short f2bf(float f) {
    unsigned int u = __float_as_uint(f);
    u += 0x7FFFu + ((u >> 16) & 1u);   // round-to-nearest-even
    return (unsigned short)(u >> 16);
}

// nontemporal loads ONLY for pure streams with zero reuse
__device__ __forceinline__ int ntl(const int* p) { return __builtin_nontemporal_load(p); }
__device__ __forceinline__ int4v ntl4(const int4v* p) { return __builtin_nontemporal_load(p); }
__device__ __forceinline__ f4v ntlf4(const f4v* p) { return __builtin_nontemporal_load(p); }

// ---------------- bucket fill ------------------------------------------------
__global__ __launch_bounds__(256) void fill_kernel(const int* __restrict__ ei,
                                                   int* __restrict__ cnt,
                                                   int* __restrict__ esrc) {
    const int xcd = blockIdx.x & (NXCD - 1);
    const int lo = xcd * (NN / NXCD);
    const int hi = (xcd == NXCD - 1) ? NN : lo + (NN / NXCD);
    const int slot = blockIdx.x >> 3;
    const int nslot = gridDim.x >> 3;
    const int4v* d4 = (const int4v*)(ei + NE);
    for (int e4 = slot * blockDim.x + threadIdx.x; e4 < NE / 4; e4 += nslot * blockDim.x) {
        int4v d = ntl4(d4 + e4);
#pragma unroll
        for (int k = 0; k < 4; ++k) {
            int dd = d[k];
            if (dd >= lo && dd < hi) {
                int pos = atomicAdd(&cnt[dd], 1);
                if (pos < CAP) {
                    esrc[(dd << 6) + pos] = ntl(ei + 4 * e4 + k);
                }
            }
        }
    }
}

__global__ __launch_bounds__(256) void dis_kernel(const int* __restrict__ cnt,
                                                  float* __restrict__ dis) {
    for (int i = blockIdx.x * blockDim.x + threadIdx.x; i < NN; i += gridDim.x * blockDim.x)
        dis[i] = rsqrtf((float)(cnt[i] + 1));   // +1 self loop
}

// ---------------- layer-1 GEMM (f32 input, nt): h2 = bf16((x@W1)*dis) -------
__global__ __launch_bounds__(256) void gemm_f32(const float* __restrict__ x,
                                                const float* __restrict__ W,
                                                const float* __restrict__ dis,
                                                unsigned short* __restrict__ h2) {
    const int K = DIN, TR = 32;
    __shared__ float xs[TR][DIN];
    const int tid = threadIdx.x;
    const int lane = tid & 63;
    const int wv = tid >> 6;
    float w[DIN];
#pragma unroll
    for (int k = 0; k < K; ++k) w[k] = W[k * 64 + lane];

    const int row0 = blockIdx.x * TR;
    const int nvec = TR * K / 4;   // NN % 32 == 0
    const f4v* srcv = (const f4v*)(x + (long long)row0 * K);
    f4v* dstv = (f4v*)&xs[0][0];
    for (int i = tid; i < nvec; i += 256) dstv[i] = ntlf4(srcv + i);
    __syncthreads();

    const int rpw = TR / 4;
#pragma unroll
    for (int rr = 0; rr < rpw; ++rr) {
        const int r = wv * rpw + rr;
        const int row = row0 + r;
        float a0 = 0.f, a1 = 0.f, a2 = 0.f, a3 = 0.f;
#pragma unroll
        for (int k = 0; k < K; k += 4) {
            float4 xv = *(const float4*)&xs[r][k];
            a0 = fmaf(xv.x, w[k + 0], a0);
            a1 = fmaf(xv.y, w[k + 1], a1);
            a2 = fmaf(xv.z, w[k + 2], a2);
            a3 = fmaf(xv.w, w[k + 3], a3);
        }
        h2[row * 64 + lane] = f2bf(((a0 + a1) + (a2 + a3)) * dis[row]);
    }
}

// ---------------- layer-2/3 GEMM (bf16 input + fused BN+ReLU) ---------------
template <int TR>
__global__ __launch_bounds__(256) void gemm_bf16(const unsigned short* __restrict__ x16,
                                                 const float* __restrict__ W,
                                                 const float* __restrict__ dis,
                                                 const float* __restrict__ sc,
                                                 const float* __restrict__ sh,
                                                 unsigned short* __restrict__ h2) {
    __shared__ float xs[TR][HDIM];
    const int tid = threadIdx.x;
    const int lane = tid & 63;
    const int wv = tid >> 6;
    float w[HDIM];
#pragma unroll
    for (int k = 0; k < HDIM; ++k) w[k] = W[k * 64 + lane];

    const int cg = tid & 7;
    float scl[8], shl[8];
#pragma unroll
    for (int j = 0; j < 8; ++j) { scl[j] = sc[cg * 8 + j]; shl[j] = sh[cg * 8 + j]; }

    const int row0 = blockIdx.x * TR;
    const int remRows = NN - row0;
    const int nvec = ((remRows >= TR) ? TR : remRows) * 8;   // u16x8 per row = 8
    const u16x8* srcv = (const u16x8*)(x16 + (long long)row0 * 64);
    for (int i = tid; i < nvec; i += 256) {
        u16x8 v = srcv[i];
        float f[8];
#pragma unroll
        for (int j = 0; j < 8; ++j)
            f[j] = fmaxf(fmaf(bf2f(v[j]), scl[j], shl[j]), 0.f);
        float* dst = &xs[0][0] + i * 8;
        ((f4v*)dst)[0] = *(f4v*)&f[0];
        ((f4v*)dst)[1] = *(f4v*)&f[4];
    }
    __syncthreads();

    const int rpw = TR / 4;
#pragma unroll
    for (int rr = 0; rr < rpw; ++rr) {
        const int r = wv * rpw + rr;
        const int row = row0 + r;
        if (row >= NN) break;
        float a0 = 0.f, a1 = 0.f, a2 = 0.f, a3 = 0.f;
#pragma unroll
        for (int k = 0; k < HDIM; k += 4) {
            float4 xv = *(const float4*)&xs[r][k];
            a0 = fmaf(xv.x, w[k + 0], a0);
            a1 = fmaf(xv.y, w[k + 1], a1);
            a2 = fmaf(xv.z, w[k + 2], a2);
            a3 = fmaf(xv.w, w[k + 3], a3);
        }
        h2[row * 64 + lane] = f2bf(((a0 + a1) + (a2 + a3)) * dis[row]);
    }
}

// ---------------- bucket gather + bf16 y + fused block stats ----------------
// int4-batched UNIFORM index loads: jb is 256B-aligned, one int4 load feeds
// 4 gathers -> VMEM/edge 2.0 -> 1.25 with no extra dependency chain (unlike
// the failed r11 shfl variant). Stale/pad slots clamp to zeroed row NN.
__global__ __launch_bounds__(256) void agg_csr(const int* __restrict__ cnt,
                                               const int* __restrict__ esrc,
                                               const float* __restrict__ dis,
                                               const unsigned short* __restrict__ h2,
                                               unsigned short* __restrict__ y16,
                                               float* __restrict__ part) {
    __shared__ float sm[8][64];
    const int tid = threadIdx.x;
    const int wv = tid >> 6;
    const int lane = tid & 63;
    const int half = lane >> 5;
    const int c = lane & 31;                 // channel-pair index
    const int node = blockIdx.x * 8 + wv * 2 + half;
    const ushort2* h2v = (const ushort2*)h2;
    ushort2 p0 = h2v[node * 32 + c];
    float ax = bf2f(p0.x), ay = bf2f(p0.y);
    const int deg = min(cnt[node], CAP);
    const int m = max(deg, __shfl_xor(deg, 32));
    const int4v* e4p = (const int4v*)(esrc + (node << 6));
    const int nq = (m + 3) >> 2;
#pragma unroll 2
    for (int tq = 0; tq < nq; ++tq) {
        int4v q = e4p[tq];                   // uniform, in-bounds (CAP slots)
#pragma unroll
        for (int k = 0; k < 4; ++k) {
            int t = tq * 4 + k;
            int s = (t < deg) ? q[k] : NN;   // pad row NN is zeroed
            ushort2 p = h2v[s * 32 + c];
            ax += bf2f(p.x);
            ay += bf2f(p.y);
        }
    }
    const float dn = dis[node];
    ax *= dn; ay *= dn;
    ushort2 o; o.x = f2bf(ax); o.y = f2bf(ay);
    ((ushort2*)y16)[node * 32 + c] = o;
    const int rl = wv * 2 + half;
    sm[rl][2 * c] = ax;
    sm[rl][2 * c + 1] = ay;
    __syncthreads();
    if (tid < 64) {
        float s = 0.f, s2 = 0.f;
#pragma unroll
        for (int r = 0; r < 8; ++r) {
            float v = sm[r][tid];
            s += v;
            s2 = fmaf(v, v, s2);
        }
        part[blockIdx.x * 128 + tid] = s;
        part[blockIdx.x * 128 + 64 + tid] = s2;
    }
}

// ---------------- partial-stats reduction (coalesced) -----------------------
__global__ __launch_bounds__(128) void stats_reduce(const float* __restrict__ part,
                                                    float* __restrict__ stats) {
    const int tid = threadIdx.x;
    const int r0 = blockIdx.x * (NAGG / 100);
    float s = 0.f;
    for (int r = r0; r < r0 + NAGG / 100; ++r) s += part[r * 128 + tid];
    atomicAdd(&stats[tid], s);
}

// ---------------- BN coefficients ----------------
__global__ __launch_bounds__(64) void bn_coef(const float* __restrict__ stats,
                                              const float* __restrict__ g,
                                              const float* __restrict__ beta,
                                              float* __restrict__ sc,
                                              float* __restrict__ sh) {
    const int c = threadIdx.x;
    const float invN = 1.0f / NN;
    float m = stats[c] * invN;
    float var = stats[64 + c] * invN - m * m;
    float s = g[c] * rsqrtf(var + EPS);
    sc[c] = s;
    sh[c] = beta[c] - m * s;
}

// ---------------- layer-3 gather + JK max (bf16 x1/x2) + final --------------
__global__ __launch_bounds__(256) void agg_final(const int* __restrict__ cnt,
                                                 const int* __restrict__ esrc,
                                                 const float* __restrict__ dis,
                                                 const unsigned short* __restrict__ h2,
                                                 const unsigned short* __restrict__ x1,
                                                 const unsigned short* __restrict__ x2,
                                                 const float* __restrict__ sc1,
                                                 const float* __restrict__ sh1,
                                                 const float* __restrict__ sc2,
                                                 const float* __restrict__ sh2,
                                                 const float* __restrict__ b3,
                                                 const float* __restrict__ Wf,
                                                 const float* __restrict__ bf,
                                                 float* __restrict__ out) {
    __shared__ float m[8][64];
    const int tid = threadIdx.x;
    const int wv = tid >> 6;
    const int lane = tid & 63;
    const int half = lane >> 5;
    const int c = lane & 31;
    const int node = blockIdx.x * 8 + wv * 2 + half;
    const ushort2* h2v = (const ushort2*)h2;
    ushort2 p0 = h2v[node * 32 + c];
    float ax = bf2f(p0.x), ay = bf2f(p0.y);
    const int deg = min(cnt[node], CAP);
    const int mm = max(deg, __shfl_xor(deg, 32));
    const int4v* e4p = (const int4v*)(esrc + (node << 6));
    const int nq = (mm + 3) >> 2;
#pragma unroll 2
    for (int tq = 0; tq < nq; ++tq) {
        int4v q = e4p[tq];
#pragma unroll
        for (int k = 0; k < 4; ++k) {
            int t = tq * 4 + k;
            int s = (t < deg) ? q[k] : NN;
            ushort2 p = h2v[s * 32 + c];
            ax += bf2f(p.x);
            ay += bf2f(p.y);
        }
    }
    const float dn = dis[node];
    const int c0 = 2 * c;
    ushort2 x1u = ((const ushort2*)x1)[node * 32 + c];
    ushort2 x2u = ((const ushort2*)x2)[node * 32 + c];
    float v3x = fmaf(ax, dn, b3[c0]);
    float v3y = fmaf(ay, dn, b3[c0 + 1]);
    float v1x = fmaxf(fmaf(bf2f(x1u.x), sc1[c0], sh1[c0]), 0.f);
    float v1y = fmaxf(fmaf(bf2f(x1u.y), sc1[c0 + 1], sh1[c0 + 1]), 0.f);
    float v2x = fmaxf(fmaf(bf2f(x2u.x), sc2[c0], sh2[c0]), 0.f);
    float v2y = fmaxf(fmaf(bf2f(x2u.y), sc2[c0 + 1], sh2[c0 + 1]), 0.f);
    const int rl = wv * 2 + half;
    m[rl][c0] = fmaxf(fmaxf(v1x, v2x), v3x);
    m[rl][c0 + 1] = fmaxf(fmaxf(v1y, v2y), v3y);
    __syncthreads();
#pragma unroll
    for (int rr = wv; rr < 8; rr += 4) {
        if (lane < DOUT) {
            float a2 = bf[lane];
#pragma unroll
            for (int k = 0; k < 64; ++k) a2 += m[rr][k] * Wf[k * DOUT + lane];
            out[(blockIdx.x * 8 + rr) * DOUT + lane] = a2;
        }
    }
}

extern "C" void kernel_launch(void* const* d_in, const int* in_sizes, int n_in,
                              void* d_out, int out_size, void* d_ws, size_t ws_size,
                              hipStream_t stream) {
    const float* node_feat = (const float*)d_in[0];
    const int*   ei        = (const int*)d_in[1];
    const float* W1 = (const float*)d_in[2];
    const float* g1 = (const float*)d_in[4];
    const float* beta1 = (const float*)d_in[5];
    const float* W2 = (const float*)d_in[6];
    const float* g2 = (const float*)d_in[8];
    const float* beta2 = (const float*)d_in[9];
    const float* W3 = (const float*)d_in[10];
    const float* b3 = (const float*)d_in[11];
    const float* Wf = (const float*)d_in[12];
    const float* bf = (const float*)d_in[13];
    float* out = (float*)d_out;

    // workspace layout
    float* ws  = (float*)d_ws;
    float* dis = ws;                                       // N f32
    unsigned short* h2 = (unsigned short*)(dis + NN);      // (N+1)*64 bf16 (+pad row)
    unsigned short* x1 = h2 + (NN + 1) * 64;               // N*64 bf16
    unsigned short* x2 = x1 + NN * 64;                     // N*64 bf16
    float* part = (float*)(x2 + NN * 64);                  // NAGG*128 f32
    float* stats = part + NAGG * 128;                      // 128
    float* sc1 = stats + 128;                              // 64
    float* sh1 = sc1 + 64;                                 // 64
    float* sc2 = sh1 + 64;                                 // 64
    float* sh2 = sc2 + 64;                                 // 64
    int* cnt  = (int*)(sh2 + 64);                          // N
    int* esrc = cnt + NN;                                  // N*CAP

    const int B = 256;
    const int gElem = 2048;
    const int gAgg = NAGG;        // 12500

    // ---- bucket build + normalization ----
    hipMemsetAsync(cnt, 0, NN * sizeof(int), stream);
    hipMemsetAsync(h2 + NN * 64, 0, 64 * sizeof(unsigned short), stream);  // pad row
    fill_kernel<<<gElem, B, 0, stream>>>(ei, cnt, esrc);
    dis_kernel<<<512, B, 0, stream>>>(cnt, dis);

    // ---- layer 1 ----
    gemm_f32<<<NN / 32, B, 0, stream>>>(node_feat, W1, dis, h2);
    agg_csr<<<gAgg, B, 0, stream>>>(cnt, esrc, dis, h2, x1, part);
    hipMemsetAsync(stats, 0, 128 * sizeof(float), stream);
    stats_reduce<<<100, 128, 0, stream>>>(part, stats);
    bn_coef<<<1, 64, 0, stream>>>(stats, g1, beta1, sc1, sh1);

    // ---- layer 2 (BN1+ReLU fused into staging) ----
    gemm_bf16<64><<<(NN + 63) / 64, B, 0, stream>>>(x1, W2, dis, sc1, sh1, h2);
    agg_csr<<<gAgg, B, 0, stream>>>(cnt, esrc, dis, h2, x2, part);
    hipMemsetAsync(stats, 0, 128 * sizeof(float), stream);
    stats_reduce<<<100, 128, 0, stream>>>(part, stats);
    bn_coef<<<1, 64, 0, stream>>>(stats, g2, beta2, sc2, sh2);

    // ---- layer 3 (BN2+ReLU fused into staging; agg fused with JK+final) ----
    gemm_bf16<64><<<(NN + 63) / 64, B, 0, stream>>>(x2, W3, dis, sc2, sh2, h2);
    agg_final<<<gAgg, B, 0, stream>>>(cnt, esrc, dis, h2, x1, x2,
                                      sc1, sh1, sc2, sh2, b3, Wf, bf, out);
}